// Round 4
// baseline (309.651 us; speedup 1.0000x reference)
//
#include <hip/hip_runtime.h>
#include <hip/hip_bf16.h>

#define NS 512
#define NV 32000
#define NB 16
#define NT 128

#ifndef __has_builtin
#define __has_builtin(x) 0
#endif

typedef int v8i __attribute__((ext_vector_type(8)));
typedef float v4f __attribute__((ext_vector_type(4)));

// ---------------------------------------------------------------------------
// e4m3fn (OCP) encode, x >= 0.
// ---------------------------------------------------------------------------
__device__ inline unsigned enc_e4m3(float x) {
    x = fminf(x, 448.0f);
    unsigned u = __float_as_uint(x);
    if (x < 0.015625f) {
        return (unsigned)(int)rintf(x * 512.0f);
    }
    unsigned u2 = u + 0x7FFFFu + ((u >> 20) & 1u);
    return (((u2 >> 23) - 120u) << 3) | ((u2 >> 20) & 7u);
}

__device__ inline unsigned pack4_e4m3(float a, float b, float c, float d) {
#if __has_builtin(__builtin_amdgcn_cvt_pk_fp8_f32)
    int v = __builtin_amdgcn_cvt_pk_fp8_f32(a, b, 0, false);
    v = __builtin_amdgcn_cvt_pk_fp8_f32(c, d, v, true);
    return (unsigned)v;
#else
    return enc_e4m3(a) | (enc_e4m3(b) << 8) | (enc_e4m3(c) << 16) | (enc_e4m3(d) << 24);
#endif
}

#define DPPMAX(x, ctrl) \
    x = fmaxf(x, __int_as_float(__builtin_amdgcn_mov_dpp(__float_as_int(x), ctrl, 0xF, 0xF, true)))
#define DPPADD(x, ctrl) \
    x = x + __int_as_float(__builtin_amdgcn_mov_dpp(__float_as_int(x), ctrl, 0xF, 0xF, true))

// ---------------------------------------------------------------------------
// K1a: per-state logZ over vocab + emission gather, COALESCED store to
// em_lin_T[s][j] = exp(em[s][ids_j]) / Z_s * 2^-18.
// Gather loads issued FIRST so they complete while the row streams (avoids
// re-fetching the row from HBM after L2 eviction).
// ---------------------------------------------------------------------------
__global__ __launch_bounds__(256) void k_emtok_T(
    const float* __restrict__ em, const int* __restrict__ ids,
    float* __restrict__ em_lin_T)
{
    const int s   = blockIdx.x;
    const int tid = threadIdx.x;
    const float* row = em + (size_t)s * NV;

    // ---- gather first (8 per thread, independent, stay in flight) ----
    int idv[8];
#pragma unroll
    for (int k = 0; k < 8; ++k) idv[k] = ids[tid + 256 * k];
    float g[8];
#pragma unroll
    for (int k = 0; k < 8; ++k) g[k] = row[idv[k]];

    // ---- stream the row for logZ ----
    float sum = 0.f;
    const float4* row4 = (const float4*)row;
#pragma unroll 4
    for (int i = 0; i < 31; ++i) {
        float4 v = row4[tid + 256 * i];
        sum += __expf(v.x) + __expf(v.y) + __expf(v.z) + __expf(v.w);
    }
    sum += __expf(row[31744 + tid]);

#pragma unroll
    for (int off = 32; off; off >>= 1) sum += __shfl_down(sum, off);
    __shared__ float red[4];
    __shared__ float s_scale;
    if ((tid & 63) == 0) red[tid >> 6] = sum;
    __syncthreads();
    if (tid == 0) s_scale = (1.0f / ((red[0] + red[1]) + (red[2] + red[3]))) * 0x1p-18f;
    __syncthreads();
    const float scale = s_scale;

#pragma unroll
    for (int k = 0; k < 8; ++k)
        em_lin_T[(size_t)s * (NB * NT) + tid + 256 * k] = __expf(g[k]) * scale;
}

// Fallback (small workspace): strided store directly to em_lin[j][s].
__global__ __launch_bounds__(256) void k_emtok_direct(
    const float* __restrict__ em, const int* __restrict__ ids,
    float* __restrict__ em_lin)
{
    const int s   = blockIdx.x;
    const int tid = threadIdx.x;
    const float* row = em + (size_t)s * NV;

    int idv[8];
#pragma unroll
    for (int k = 0; k < 8; ++k) idv[k] = ids[tid + 256 * k];
    float g[8];
#pragma unroll
    for (int k = 0; k < 8; ++k) g[k] = row[idv[k]];

    float sum = 0.f;
    const float4* row4 = (const float4*)row;
#pragma unroll 4
    for (int i = 0; i < 31; ++i) {
        float4 v = row4[tid + 256 * i];
        sum += __expf(v.x) + __expf(v.y) + __expf(v.z) + __expf(v.w);
    }
    sum += __expf(row[31744 + tid]);
#pragma unroll
    for (int off = 32; off; off >>= 1) sum += __shfl_down(sum, off);
    __shared__ float red[4];
    __shared__ float s_scale;
    if ((tid & 63) == 0) red[tid >> 6] = sum;
    __syncthreads();
    if (tid == 0) s_scale = (1.0f / ((red[0] + red[1]) + (red[2] + red[3]))) * 0x1p-18f;
    __syncthreads();
    const float scale = s_scale;
#pragma unroll
    for (int k = 0; k < 8; ++k)
        em_lin[(size_t)(tid + 256 * k) * NS + s] = __expf(g[k]) * scale;
}

// ---------------------------------------------------------------------------
// K1b: transpose em_lin_T [512][2048] -> em_lin [2048][512]
// ---------------------------------------------------------------------------
__global__ __launch_bounds__(256) void k_tr(
    const float* __restrict__ emT, float* __restrict__ em_lin)
{
    __shared__ float tile[32][33];
    const int jb = blockIdx.x * 32;
    const int sb = blockIdx.y * 32;
    const int cc = threadIdx.x & 31;
    const int rr = threadIdx.x >> 5;
#pragma unroll
    for (int i = 0; i < 4; ++i) {
        int r = rr + 8 * i;
        tile[r][cc] = emT[(size_t)(sb + r) * (NB * NT) + jb + cc];
    }
    __syncthreads();
#pragma unroll
    for (int i = 0; i < 4; ++i) {
        int r = rr + 8 * i;
        em_lin[(size_t)(jb + r) * NS + sb + cc] = tile[cc][r];
    }
}

// ---------------------------------------------------------------------------
// K2a: zscale[k] = 1024 / sum_d exp(tm[k][d])
// ---------------------------------------------------------------------------
__global__ __launch_bounds__(64) void k_z(
    const float* __restrict__ tm, float* __restrict__ zscale)
{
    const int k    = blockIdx.x;
    const int lane = threadIdx.x;
    const float* row = tm + (size_t)k * NS;

    float4 a = ((const float4*)row)[lane * 2];
    float4 b = ((const float4*)row)[lane * 2 + 1];
    float sum = ((__expf(a.x) + __expf(a.y)) + (__expf(a.z) + __expf(a.w)))
              + ((__expf(b.x) + __expf(b.y)) + (__expf(b.z) + __expf(b.w)));
#pragma unroll
    for (int off = 32; off; off >>= 1) sum += __shfl_down(sum, off);
    if (lane == 0) zscale[k] = 1024.0f / sum;
}

// ---------------------------------------------------------------------------
// K2b: PT[d][k] = exp(tm[k][d]) * zscale[k], e4m3 fp8, via LDS 64x64 tile
// transpose -> coalesced uint4 stores. grid (8,8), 256 threads.
// ---------------------------------------------------------------------------
__global__ __launch_bounds__(256) void k_pt2(
    const float* __restrict__ tm, const float* __restrict__ zscale,
    unsigned char* __restrict__ PT)
{
    __shared__ float tile[64][65];
    __shared__ float zs[64];
    const int kb  = blockIdx.x * 64;
    const int db  = blockIdx.y * 64;
    const int tid = threadIdx.x;
    const int c   = tid & 63;
    const int r0  = tid >> 6;

    if (tid < 64) zs[tid] = zscale[kb + tid];
#pragma unroll
    for (int i = 0; i < 16; ++i) {
        int r = r0 + 4 * i;
        tile[r][c] = tm[(size_t)(kb + r) * NS + db + c];
    }
    __syncthreads();

    const int d  = tid >> 2;
    const int ks = (tid & 3) * 16;
    unsigned px[4];
#pragma unroll
    for (int gq = 0; gq < 4; ++gq) {
        int k0 = ks + gq * 4;
        px[gq] = pack4_e4m3(__expf(tile[k0 + 0][d]) * zs[k0 + 0],
                            __expf(tile[k0 + 1][d]) * zs[k0 + 1],
                            __expf(tile[k0 + 2][d]) * zs[k0 + 2],
                            __expf(tile[k0 + 3][d]) * zs[k0 + 3]);
    }
    uint4 o; o.x = px[0]; o.y = px[1]; o.z = px[2]; o.w = px[3];
    *(uint4*)(PT + (size_t)(db + d) * NS + kb + ks) = o;
}

// ---------------------------------------------------------------------------
// K3: the scan. ONE block, 512 threads (8 waves), all 16 batches as MFMA M.
// v2: shift init = +18 (2^-18 folded into em_lin at t=0 — BUGFIX);
//     single-buffer Ew; B2 barrier removed (all-thread wm2 reduce);
//     stepped pointers for epf loads.
// ---------------------------------------------------------------------------
__global__ __launch_bounds__(512, 2) void k_scan(
    const float* __restrict__ em_lin, const unsigned char* __restrict__ PT,
    const float* __restrict__ p, float* __restrict__ out)
{
    const int tid = threadIdx.x;
    const int w   = tid >> 6;          // wave 0..7
    const int l   = tid & 63;          // lane
    const int lc  = l & 15;
    const int lq  = l >> 4;

    __shared__ unsigned int Ew[16 * 128];     // 8 KB, [m][chunk^m swizzled]
    __shared__ float wm2[8][16];              // [wave][batch]
    __shared__ int   sbuf[16];

    // ---- load B fragments (P, once) ----
    v8i B[4][4];
#pragma unroll
    for (int nt = 0; nt < 4; ++nt) {
#pragma unroll
        for (int kt = 0; kt < 4; ++kt) {
            const uint4* src = (const uint4*)(PT + (size_t)((w * 4 + nt) * 16 + lc) * NS + kt * 128 + lq * 32);
            uint4 lo = src[0], hi = src[1];
            v8i bb;
            bb[0] = (int)lo.x; bb[1] = (int)lo.y; bb[2] = (int)lo.z; bb[3] = (int)lo.w;
            bb[4] = (int)hi.x; bb[5] = (int)hi.y; bb[6] = (int)hi.z; bb[7] = (int)hi.w;
            B[nt][kt] = bb;
        }
    }

    // ---- prior softmax denominator ----
    float zp = 0.f;
#pragma unroll
    for (int i = 0; i < 8; ++i) zp += __expf(p[l * 8 + i]);
    DPPADD(zp, 0x111); DPPADD(zp, 0x112); DPPADD(zp, 0x114); DPPADD(zp, 0x118);
    float Zp = __int_as_float(__builtin_amdgcn_readlane(__float_as_int(zp), 15))
             + __int_as_float(__builtin_amdgcn_readlane(__float_as_int(zp), 31))
             + __int_as_float(__builtin_amdgcn_readlane(__float_as_int(zp), 47))
             + __int_as_float(__builtin_amdgcn_readlane(__float_as_int(zp), 63));
    const float invZp = 1.0f / Zp;

    const int dbase0 = w * 64 + lc;     // d for nt: dbase0 + 16*nt

    // ---- alpha_0 (linear, 2^-18 embedded -> shift starts at 18) ----
    float alpha[4][4];   // [nt][r], batch m = 4*lq + r
#pragma unroll
    for (int nt = 0; nt < 4; ++nt) {
        float pl = __expf(p[dbase0 + 16 * nt]) * invZp;
#pragma unroll
        for (int r = 0; r < 4; ++r)
            alpha[nt][r] = pl * em_lin[(4 * lq + r) * (NT * NS) + dbase0 + 16 * nt];
    }

    int shift[4] = {18, 18, 18, 18};
    const unsigned sel1 = (l & 1) ? 0x07030501u : 0x02060004u;
    const unsigned sel2 = (l & 2) ? 0x07060302u : 0x01000504u;
    const int mrow = 4 * lq + (l & 3);

    // stepped emission pointers, one per r (batch row), starting at t=1
    const float* ep[4];
#pragma unroll
    for (int r = 0; r < 4; ++r)
        ep[r] = em_lin + (size_t)(4 * lq + r) * (NT * NS) + NS + dbase0;

    for (int t = 1; t < NT; ++t) {
        // ---- prefetch em (consumed at end of iteration) ----
        float epf[4][4];
#pragma unroll
        for (int nt = 0; nt < 4; ++nt)
#pragma unroll
            for (int r = 0; r < 4; ++r)
                epf[nt][r] = ep[r][16 * nt];
#pragma unroll
        for (int r = 0; r < 4; ++r) ep[r] += NS;

        // ---- per-batch wave max -> wm2[w][m] ----
#pragma unroll
        for (int r = 0; r < 4; ++r) {
            float mx = fmaxf(fmaxf(alpha[0][r], alpha[1][r]), fmaxf(alpha[2][r], alpha[3][r]));
            DPPMAX(mx, 0x111); DPPMAX(mx, 0x112); DPPMAX(mx, 0x114); DPPMAX(mx, 0x118);
            if (lc == 15) wm2[w][4 * lq + r] = mx;
        }
        __syncthreads();                                    // B1

        // ---- all-thread cross-wave reduce (broadcast reads, no 2nd barrier)
        float4 M4;
        {
            float4 v0 = *(const float4*)&wm2[0][4 * lq];
            float4 v1 = *(const float4*)&wm2[1][4 * lq];
            float4 v2 = *(const float4*)&wm2[2][4 * lq];
            float4 v3 = *(const float4*)&wm2[3][4 * lq];
            float4 v4 = *(const float4*)&wm2[4][4 * lq];
            float4 v5 = *(const float4*)&wm2[5][4 * lq];
            float4 v6 = *(const float4*)&wm2[6][4 * lq];
            float4 v7 = *(const float4*)&wm2[7][4 * lq];
            M4.x = fmaxf(fmaxf(fmaxf(v0.x, v1.x), fmaxf(v2.x, v3.x)),
                         fmaxf(fmaxf(v4.x, v5.x), fmaxf(v6.x, v7.x)));
            M4.y = fmaxf(fmaxf(fmaxf(v0.y, v1.y), fmaxf(v2.y, v3.y)),
                         fmaxf(fmaxf(v4.y, v5.y), fmaxf(v6.y, v7.y)));
            M4.z = fmaxf(fmaxf(fmaxf(v0.z, v1.z), fmaxf(v2.z, v3.z)),
                         fmaxf(fmaxf(v4.z, v5.z), fmaxf(v6.z, v7.z)));
            M4.w = fmaxf(fmaxf(fmaxf(v0.w, v1.w), fmaxf(v2.w, v3.w)),
                         fmaxf(fmaxf(v4.w, v5.w), fmaxf(v6.w, v7.w)));
        }
        float mbv[4] = {M4.x, M4.y, M4.z, M4.w};
        float sc[4];
#pragma unroll
        for (int r = 0; r < 4; ++r) {
            int Eb = (int)(__float_as_uint(mbv[r]) >> 23);
            sc[r] = __uint_as_float((unsigned)(261 - Eb) << 23);  // 2^(134-Eb)
            shift[r] += Eb - 126;
        }

        // ---- e -> fp8, DPP 4x4 byte transpose, swizzled LDS write ----
#pragma unroll
        for (int nt = 0; nt < 4; ++nt) {
            unsigned dw = pack4_e4m3(alpha[nt][0] * sc[0], alpha[nt][1] * sc[1],
                                     alpha[nt][2] * sc[2], alpha[nt][3] * sc[3]);
            int tmp = __builtin_amdgcn_mov_dpp((int)dw, 0xB1, 0xF, 0xF, true);
            dw = __builtin_amdgcn_perm(dw, (unsigned)tmp, sel1);
            tmp = __builtin_amdgcn_mov_dpp((int)dw, 0x4E, 0xF, 0xF, true);
            dw = __builtin_amdgcn_perm(dw, (unsigned)tmp, sel2);
            int chunk = ((w * 4 + nt) ^ mrow) & 31;
            Ew[mrow * 128 + chunk * 4 + (lc >> 2)] = dw;
        }
        __syncthreads();                                    // B3

        // ---- A fragments from LDS (swizzled) ----
        v8i A[4];
        const uint4* eb = (const uint4*)&Ew[0];
#pragma unroll
        for (int kt = 0; kt < 4; ++kt) {
            uint4 lo = eb[lc * 32 + (((kt * 8 + lq * 2 + 0) ^ lc) & 31)];
            uint4 hi = eb[lc * 32 + (((kt * 8 + lq * 2 + 1) ^ lc) & 31)];
            v8i aa;
            aa[0] = (int)lo.x; aa[1] = (int)lo.y; aa[2] = (int)lo.z; aa[3] = (int)lo.w;
            aa[4] = (int)hi.x; aa[5] = (int)hi.y; aa[6] = (int)hi.z; aa[7] = (int)hi.w;
            A[kt] = aa;
        }

        // ---- MFMA: Y = E . P ----
        v4f C[4];
#pragma unroll
        for (int nt = 0; nt < 4; ++nt) { C[nt][0] = 0.f; C[nt][1] = 0.f; C[nt][2] = 0.f; C[nt][3] = 0.f; }
#pragma unroll
        for (int kt = 0; kt < 4; ++kt)
#pragma unroll
            for (int nt = 0; nt < 4; ++nt)
                C[nt] = __builtin_amdgcn_mfma_scale_f32_16x16x128_f8f6f4(
                            A[kt], B[nt][kt], C[nt], 0, 0, 0, 0x7F7F7F7F, 0, 0x7F7F7F7F);

        // ---- alpha update (linear) ----
#pragma unroll
        for (int nt = 0; nt < 4; ++nt)
#pragma unroll
            for (int r = 0; r < 4; ++r)
                alpha[nt][r] = C[nt][r] * epf[nt][r];
    }

    // ---- final: loss = -(ln2/16) * sum_b (log2(sum_d alpha) + shift_b) ----
#pragma unroll
    for (int r = 0; r < 4; ++r) {
        float sm = ((alpha[0][r] + alpha[1][r]) + (alpha[2][r] + alpha[3][r]));
        DPPADD(sm, 0x111); DPPADD(sm, 0x112); DPPADD(sm, 0x114); DPPADD(sm, 0x118);
        if (lc == 15) wm2[w][4 * lq + r] = sm;
        if (w == 0 && lc == 0) sbuf[4 * lq + r] = shift[r];
    }
    __syncthreads();
    if (w == 0 && l < 16) {
        float s8 = 0.f;
#pragma unroll
        for (int j = 0; j < 8; ++j) s8 += wm2[j][l];
        float L2 = __log2f(s8) + (float)sbuf[l];
        DPPADD(L2, 0x111); DPPADD(L2, 0x112); DPPADD(L2, 0x114); DPPADD(L2, 0x118);
        if (l == 15) out[0] = -(0.693147180559945f / 16.0f) * L2;
    }
}

// ---------------------------------------------------------------------------
extern "C" void kernel_launch(void* const* d_in, const int* in_sizes, int n_in,
                              void* d_out, int out_size, void* d_ws, size_t ws_size,
                              hipStream_t stream)
{
    const int*   ids = (const int*)d_in[0];   // [16][128]
    const float* em  = (const float*)d_in[1]; // [512][32000]
    const float* tm  = (const float*)d_in[2]; // [512][512]
    const float* p   = (const float*)d_in[3]; // [512]
    float* out = (float*)d_out;

    // layout: em_lin [0,4M), PT [4M,4M+256K), zscale [4M+256K, +2K),
    //         emT [4M+512K, 8.5M)
    float*          em_lin = (float*)d_ws;
    unsigned char*  PT     = (unsigned char*)d_ws + ((size_t)4 << 20);
    float*          zscale = (float*)((unsigned char*)d_ws + ((size_t)4 << 20) + ((size_t)256 << 10));
    float*          emT    = (float*)((unsigned char*)d_ws + ((size_t)4 << 20) + ((size_t)512 << 10));

    const bool big_ws = ws_size >= (((size_t)8 << 20) + ((size_t)512 << 10));

    if (big_ws) {
        k_emtok_T<<<NS, 256, 0, stream>>>(em, ids, emT);
        k_tr<<<dim3(64, 16), 256, 0, stream>>>(emT, em_lin);
    } else {
        k_emtok_direct<<<NS, 256, 0, stream>>>(em, ids, em_lin);
    }
    k_z<<<NS, 64, 0, stream>>>(tm, zscale);
    k_pt2<<<dim3(8, 8), 256, 0, stream>>>(tm, zscale, PT);
    k_scan<<<1, 512, 0, stream>>>(em_lin, PT, p, out);
}

// Round 5
// 295.496 us; speedup vs baseline: 1.0479x; 1.0479x over previous
//
#include <hip/hip_runtime.h>
#include <hip/hip_bf16.h>

#define NS 512
#define NV 32000
#define NB 16
#define NT 128

#ifndef __has_builtin
#define __has_builtin(x) 0
#endif

typedef int v8i __attribute__((ext_vector_type(8)));
typedef float v4f __attribute__((ext_vector_type(4)));

// ---------------------------------------------------------------------------
// e4m3fn (OCP) encode, x >= 0.
// ---------------------------------------------------------------------------
__device__ inline unsigned enc_e4m3(float x) {
    x = fminf(x, 448.0f);
    unsigned u = __float_as_uint(x);
    if (x < 0.015625f) {
        return (unsigned)(int)rintf(x * 512.0f);
    }
    unsigned u2 = u + 0x7FFFFu + ((u >> 20) & 1u);
    return (((u2 >> 23) - 120u) << 3) | ((u2 >> 20) & 7u);
}

__device__ inline unsigned pack4_e4m3(float a, float b, float c, float d) {
#if __has_builtin(__builtin_amdgcn_cvt_pk_fp8_f32)
    int v = __builtin_amdgcn_cvt_pk_fp8_f32(a, b, 0, false);
    v = __builtin_amdgcn_cvt_pk_fp8_f32(c, d, v, true);
    return (unsigned)v;
#else
    return enc_e4m3(a) | (enc_e4m3(b) << 8) | (enc_e4m3(c) << 16) | (enc_e4m3(d) << 24);
#endif
}

// DPP all-lane reduce within a row of 16: ror8, ror4, quad xor1, quad xor2.
#define DPPMAX(x, ctrl) \
    x = fmaxf(x, __int_as_float(__builtin_amdgcn_mov_dpp(__float_as_int(x), ctrl, 0xF, 0xF, true)))
#define DPPADD(x, ctrl) \
    x = x + __int_as_float(__builtin_amdgcn_mov_dpp(__float_as_int(x), ctrl, 0xF, 0xF, true))

// ---------------------------------------------------------------------------
// K1a: per-state logZ over vocab + emission gather, COALESCED store to
// em_lin_T[s][j] = exp(em[s][ids_j]) / Z_s * 2^-18.
// ---------------------------------------------------------------------------
__global__ __launch_bounds__(256) void k_emtok_T(
    const float* __restrict__ em, const int* __restrict__ ids,
    float* __restrict__ em_lin_T)
{
    const int s   = blockIdx.x;
    const int tid = threadIdx.x;
    const float* row = em + (size_t)s * NV;

    int idv[8];
#pragma unroll
    for (int k = 0; k < 8; ++k) idv[k] = ids[tid + 256 * k];
    float g[8];
#pragma unroll
    for (int k = 0; k < 8; ++k) g[k] = row[idv[k]];

    float sum = 0.f;
    const float4* row4 = (const float4*)row;
#pragma unroll 4
    for (int i = 0; i < 31; ++i) {
        float4 v = row4[tid + 256 * i];
        sum += __expf(v.x) + __expf(v.y) + __expf(v.z) + __expf(v.w);
    }
    sum += __expf(row[31744 + tid]);

#pragma unroll
    for (int off = 32; off; off >>= 1) sum += __shfl_down(sum, off);
    __shared__ float red[4];
    __shared__ float s_scale;
    if ((tid & 63) == 0) red[tid >> 6] = sum;
    __syncthreads();
    if (tid == 0) s_scale = (1.0f / ((red[0] + red[1]) + (red[2] + red[3]))) * 0x1p-18f;
    __syncthreads();
    const float scale = s_scale;

#pragma unroll
    for (int k = 0; k < 8; ++k)
        em_lin_T[(size_t)s * (NB * NT) + tid + 256 * k] = __expf(g[k]) * scale;
}

// Fallback (small workspace): strided store directly to em_lin[j][s].
__global__ __launch_bounds__(256) void k_emtok_direct(
    const float* __restrict__ em, const int* __restrict__ ids,
    float* __restrict__ em_lin)
{
    const int s   = blockIdx.x;
    const int tid = threadIdx.x;
    const float* row = em + (size_t)s * NV;

    int idv[8];
#pragma unroll
    for (int k = 0; k < 8; ++k) idv[k] = ids[tid + 256 * k];
    float g[8];
#pragma unroll
    for (int k = 0; k < 8; ++k) g[k] = row[idv[k]];

    float sum = 0.f;
    const float4* row4 = (const float4*)row;
#pragma unroll 4
    for (int i = 0; i < 31; ++i) {
        float4 v = row4[tid + 256 * i];
        sum += __expf(v.x) + __expf(v.y) + __expf(v.z) + __expf(v.w);
    }
    sum += __expf(row[31744 + tid]);
#pragma unroll
    for (int off = 32; off; off >>= 1) sum += __shfl_down(sum, off);
    __shared__ float red[4];
    __shared__ float s_scale;
    if ((tid & 63) == 0) red[tid >> 6] = sum;
    __syncthreads();
    if (tid == 0) s_scale = (1.0f / ((red[0] + red[1]) + (red[2] + red[3]))) * 0x1p-18f;
    __syncthreads();
    const float scale = s_scale;
#pragma unroll
    for (int k = 0; k < 8; ++k)
        em_lin[(size_t)(tid + 256 * k) * NS + s] = __expf(g[k]) * scale;
}

// ---------------------------------------------------------------------------
// K1b: transpose em_lin_T [512][2048] -> em_lin [2048][512]
// ---------------------------------------------------------------------------
__global__ __launch_bounds__(256) void k_tr(
    const float* __restrict__ emT, float* __restrict__ em_lin)
{
    __shared__ float tile[32][33];
    const int jb = blockIdx.x * 32;
    const int sb = blockIdx.y * 32;
    const int cc = threadIdx.x & 31;
    const int rr = threadIdx.x >> 5;
#pragma unroll
    for (int i = 0; i < 4; ++i) {
        int r = rr + 8 * i;
        tile[r][cc] = emT[(size_t)(sb + r) * (NB * NT) + jb + cc];
    }
    __syncthreads();
#pragma unroll
    for (int i = 0; i < 4; ++i) {
        int r = rr + 8 * i;
        em_lin[(size_t)(jb + r) * NS + sb + cc] = tile[cc][r];
    }
}

// ---------------------------------------------------------------------------
// K2a: zscale[k] = 1024 / sum_d exp(tm[k][d])
// ---------------------------------------------------------------------------
__global__ __launch_bounds__(64) void k_z(
    const float* __restrict__ tm, float* __restrict__ zscale)
{
    const int k    = blockIdx.x;
    const int lane = threadIdx.x;
    const float* row = tm + (size_t)k * NS;

    float4 a = ((const float4*)row)[lane * 2];
    float4 b = ((const float4*)row)[lane * 2 + 1];
    float sum = ((__expf(a.x) + __expf(a.y)) + (__expf(a.z) + __expf(a.w)))
              + ((__expf(b.x) + __expf(b.y)) + (__expf(b.z) + __expf(b.w)));
#pragma unroll
    for (int off = 32; off; off >>= 1) sum += __shfl_down(sum, off);
    if (lane == 0) zscale[k] = 1024.0f / sum;
}

// ---------------------------------------------------------------------------
// K2b: PT[d][k] = exp(tm[k][d]) * zscale[k], e4m3 fp8, LDS-transposed tiles.
// ---------------------------------------------------------------------------
__global__ __launch_bounds__(256) void k_pt2(
    const float* __restrict__ tm, const float* __restrict__ zscale,
    unsigned char* __restrict__ PT)
{
    __shared__ float tile[64][65];
    __shared__ float zs[64];
    const int kb  = blockIdx.x * 64;
    const int db  = blockIdx.y * 64;
    const int tid = threadIdx.x;
    const int c   = tid & 63;
    const int r0  = tid >> 6;

    if (tid < 64) zs[tid] = zscale[kb + tid];
#pragma unroll
    for (int i = 0; i < 16; ++i) {
        int r = r0 + 4 * i;
        tile[r][c] = tm[(size_t)(kb + r) * NS + db + c];
    }
    __syncthreads();

    const int d  = tid >> 2;
    const int ks = (tid & 3) * 16;
    unsigned px[4];
#pragma unroll
    for (int gq = 0; gq < 4; ++gq) {
        int k0 = ks + gq * 4;
        px[gq] = pack4_e4m3(__expf(tile[k0 + 0][d]) * zs[k0 + 0],
                            __expf(tile[k0 + 1][d]) * zs[k0 + 1],
                            __expf(tile[k0 + 2][d]) * zs[k0 + 2],
                            __expf(tile[k0 + 3][d]) * zs[k0 + 3]);
    }
    uint4 o; o.x = px[0]; o.y = px[1]; o.z = px[2]; o.w = px[3];
    *(uint4*)(PT + (size_t)(db + d) * NS + kb + ks) = o;
}

// ---------------------------------------------------------------------------
// K3 v3: ONE barrier per step, per-wave MX block scales.
//   Producer (pre-barrier): per-(wave,batch) local max (DPP all-lane reduce),
//     quantize E with local scale, write Ew + byte-exponent table Stab.
//   Consumer (post-barrier): read Stab (8 b32), compute per-batch global
//     exponent G locally, feed byteS-G+127 as per-lane e8m0 A-scales to
//     mfma_scale (replicated x4 so opsel is irrelevant), shift += G+1.
// ---------------------------------------------------------------------------
__global__ __launch_bounds__(512, 2) void k_scan(
    const float* __restrict__ em_lin, const unsigned char* __restrict__ PT,
    const float* __restrict__ p, float* __restrict__ out)
{
    const int tid = threadIdx.x;
    const int w   = tid >> 6;          // wave 0..7
    const int l   = tid & 63;          // lane
    const int lc  = l & 15;
    const int lq  = l >> 4;

    __shared__ unsigned int Ew[2][16 * 128];   // 2 x 8 KB
    __shared__ unsigned int Stab[2][32];       // [w*4+lq] -> bytes r=0..3
    __shared__ float wm2[8][16];
    __shared__ float sbuf[16];

    // ---- load B fragments (P, once) ----
    v8i B[4][4];
#pragma unroll
    for (int nt = 0; nt < 4; ++nt) {
#pragma unroll
        for (int kt = 0; kt < 4; ++kt) {
            const uint4* src = (const uint4*)(PT + (size_t)((w * 4 + nt) * 16 + lc) * NS + kt * 128 + lq * 32);
            uint4 lo = src[0], hi = src[1];
            v8i bb;
            bb[0] = (int)lo.x; bb[1] = (int)lo.y; bb[2] = (int)lo.z; bb[3] = (int)lo.w;
            bb[4] = (int)hi.x; bb[5] = (int)hi.y; bb[6] = (int)hi.z; bb[7] = (int)hi.w;
            B[nt][kt] = bb;
        }
    }

    // ---- prior softmax denominator ----
    float zp = 0.f;
#pragma unroll
    for (int i = 0; i < 8; ++i) zp += __expf(p[l * 8 + i]);
    DPPADD(zp, 0x128); DPPADD(zp, 0x124); DPPADD(zp, 0xB1); DPPADD(zp, 0x4E);
    float Zp = __int_as_float(__builtin_amdgcn_readlane(__float_as_int(zp), 0))
             + __int_as_float(__builtin_amdgcn_readlane(__float_as_int(zp), 16))
             + __int_as_float(__builtin_amdgcn_readlane(__float_as_int(zp), 32))
             + __int_as_float(__builtin_amdgcn_readlane(__float_as_int(zp), 48));
    const float invZp = 1.0f / Zp;

    const int dbase0 = w * 64 + lc;     // d for nt: dbase0 + 16*nt

    // ---- alpha_0 (linear; 2^-18 embedded in em_lin -> shift starts at 18) ----
    float alpha[4][4];   // [nt][r], batch m = 4*lq + r
#pragma unroll
    for (int nt = 0; nt < 4; ++nt) {
        float pl = __expf(p[dbase0 + 16 * nt]) * invZp;
#pragma unroll
        for (int r = 0; r < 4; ++r)
            alpha[nt][r] = pl * em_lin[(4 * lq + r) * (NT * NS) + dbase0 + 16 * nt];
    }

    int gsum = 0;   // accumulates (G_t + 1) for batch lc (every thread, batch=lc)
    const unsigned sel1 = (l & 1) ? 0x07030501u : 0x02060004u;
    const unsigned sel2 = (l & 2) ? 0x07060302u : 0x01000504u;
    const int mrow = 4 * lq + (l & 3);

    const float* ep[4];
#pragma unroll
    for (int r = 0; r < 4; ++r)
        ep[r] = em_lin + (size_t)(4 * lq + r) * (NT * NS) + NS + dbase0;

    int buf = 0;
    for (int t = 1; t < NT; ++t) {
        // ---- prefetch em (consumed at end of iteration) ----
        float epf[4][4];
#pragma unroll
        for (int nt = 0; nt < 4; ++nt)
#pragma unroll
            for (int r = 0; r < 4; ++r)
                epf[nt][r] = ep[r][16 * nt];
#pragma unroll
        for (int r = 0; r < 4; ++r) ep[r] += NS;

        // ---- producer: per-(wave,batch) max, all-lane ----
        unsigned byteS[4];
        float sc[4];
#pragma unroll
        for (int r = 0; r < 4; ++r) {
            float mx = fmaxf(fmaxf(alpha[0][r], alpha[1][r]), fmaxf(alpha[2][r], alpha[3][r]));
            DPPMAX(mx, 0x128); DPPMAX(mx, 0x124); DPPMAX(mx, 0xB1); DPPMAX(mx, 0x4E);
            unsigned eb = __float_as_uint(mx) >> 23;
            eb = eb < 7u ? 7u : (eb > 254u ? 254u : eb);
            byteS[r] = eb;
            sc[r] = __uint_as_float((261u - eb) << 23);   // 2^(134-eb): local max -> ~128
        }
        if (lc == 0)
            Stab[buf][w * 4 + lq] = byteS[0] | (byteS[1] << 8) | (byteS[2] << 16) | (byteS[3] << 24);

        // ---- e -> fp8 (local scale), DPP 4x4 byte transpose, Ew write ----
#pragma unroll
        for (int nt = 0; nt < 4; ++nt) {
            unsigned dw = pack4_e4m3(alpha[nt][0] * sc[0], alpha[nt][1] * sc[1],
                                     alpha[nt][2] * sc[2], alpha[nt][3] * sc[3]);
            int tmp = __builtin_amdgcn_mov_dpp((int)dw, 0xB1, 0xF, 0xF, true);
            dw = __builtin_amdgcn_perm(dw, (unsigned)tmp, sel1);
            tmp = __builtin_amdgcn_mov_dpp((int)dw, 0x4E, 0xF, 0xF, true);
            dw = __builtin_amdgcn_perm(dw, (unsigned)tmp, sel2);
            int chunk = ((w * 4 + nt) ^ mrow) & 31;
            Ew[buf][mrow * 128 + chunk * 4 + (lc >> 2)] = dw;
        }
        __syncthreads();                                    // the ONE barrier

        // ---- consumer: scale bytes + per-batch global exponent G ----
        const unsigned sh = (lc & 3) * 8;
        unsigned bS[8];
#pragma unroll
        for (int w2 = 0; w2 < 8; ++w2)
            bS[w2] = (Stab[buf][w2 * 4 + (lc >> 2)] >> sh) & 0xFFu;
        unsigned byteG = bS[0];
#pragma unroll
        for (int w2 = 1; w2 < 8; ++w2) byteG = byteG > bS[w2] ? byteG : bS[w2];
        gsum += (int)byteG - 126;                 // (G + 1), G = byteG - 127

        int sA[4];
#pragma unroll
        for (int kt = 0; kt < 4; ++kt) {
            int sb = (int)bS[(kt * 4 + lq) >> 1] + 127 - (int)byteG;
            sb = sb < 0 ? 0 : sb;
            sA[kt] = sb * 0x01010101;             // replicate byte -> opsel-proof
        }

        // ---- A fragments from LDS (swizzled) ----
        v8i A[4];
        const uint4* eb4 = (const uint4*)&Ew[buf][0];
#pragma unroll
        for (int kt = 0; kt < 4; ++kt) {
            uint4 lo = eb4[lc * 32 + (((kt * 8 + lq * 2 + 0) ^ lc) & 31)];
            uint4 hi = eb4[lc * 32 + (((kt * 8 + lq * 2 + 1) ^ lc) & 31)];
            v8i aa;
            aa[0] = (int)lo.x; aa[1] = (int)lo.y; aa[2] = (int)lo.z; aa[3] = (int)lo.w;
            aa[4] = (int)hi.x; aa[5] = (int)hi.y; aa[6] = (int)hi.z; aa[7] = (int)hi.w;
            A[kt] = aa;
        }

        // ---- MFMA with per-lane A block scales ----
        v4f C[4];
#pragma unroll
        for (int nt = 0; nt < 4; ++nt) { C[nt][0] = 0.f; C[nt][1] = 0.f; C[nt][2] = 0.f; C[nt][3] = 0.f; }
#pragma unroll
        for (int kt = 0; kt < 4; ++kt)
#pragma unroll
            for (int nt = 0; nt < 4; ++nt)
                C[nt] = __builtin_amdgcn_mfma_scale_f32_16x16x128_f8f6f4(
                            A[kt], B[nt][kt], C[nt], 0, 0, 0, sA[kt], 0, 0x7F7F7F7F);

        // ---- alpha update (linear) ----
#pragma unroll
        for (int nt = 0; nt < 4; ++nt)
#pragma unroll
            for (int r = 0; r < 4; ++r)
                alpha[nt][r] = C[nt][r] * epf[nt][r];

        buf ^= 1;
    }

    // ---- final: loss = -(ln2/16) * sum_b (log2(sum_d alpha_b) + 18 + gsum_b) ----
#pragma unroll
    for (int r = 0; r < 4; ++r) {
        float sm = ((alpha[0][r] + alpha[1][r]) + (alpha[2][r] + alpha[3][r]));
        DPPADD(sm, 0x128); DPPADD(sm, 0x124); DPPADD(sm, 0xB1); DPPADD(sm, 0x4E);
        if (lc == 0) wm2[w][4 * lq + r] = sm;
    }
    if (tid < 16) sbuf[tid] = (float)gsum;    // thread tid has lc==tid
    __syncthreads();
    if (w == 0) {
        const int li = l & 15;
        float s8 = 0.f;
#pragma unroll
        for (int j = 0; j < 8; ++j) s8 += wm2[j][li];
        float L2 = __log2f(s8) + 18.0f + sbuf[li];
        DPPADD(L2, 0x128); DPPADD(L2, 0x124); DPPADD(L2, 0xB1); DPPADD(L2, 0x4E);
        if (l == 0) out[0] = -(0.693147180559945f / 16.0f) * L2;
    }
}

// ---------------------------------------------------------------------------
extern "C" void kernel_launch(void* const* d_in, const int* in_sizes, int n_in,
                              void* d_out, int out_size, void* d_ws, size_t ws_size,
                              hipStream_t stream)
{
    const int*   ids = (const int*)d_in[0];   // [16][128]
    const float* em  = (const float*)d_in[1]; // [512][32000]
    const float* tm  = (const float*)d_in[2]; // [512][512]
    const float* p   = (const float*)d_in[3]; // [512]
    float* out = (float*)d_out;

    float*          em_lin = (float*)d_ws;
    unsigned char*  PT     = (unsigned char*)d_ws + ((size_t)4 << 20);
    float*          zscale = (float*)((unsigned char*)d_ws + ((size_t)4 << 20) + ((size_t)256 << 10));
    float*          emT    = (float*)((unsigned char*)d_ws + ((size_t)4 << 20) + ((size_t)512 << 10));

    const bool big_ws = ws_size >= (((size_t)8 << 20) + ((size_t)512 << 10));

    if (big_ws) {
        k_emtok_T<<<NS, 256, 0, stream>>>(em, ids, emT);
        k_tr<<<dim3(64, 16), 256, 0, stream>>>(emT, em_lin);
    } else {
        k_emtok_direct<<<NS, 256, 0, stream>>>(em, ids, em_lin);
    }
    k_z<<<NS, 64, 0, stream>>>(tm, zscale);
    k_pt2<<<dim3(8, 8), 256, 0, stream>>>(tm, zscale, PT);
    k_scan<<<1, 512, 0, stream>>>(em_lin, PT, p, out);
}

// Round 6
// 244.750 us; speedup vs baseline: 1.2652x; 1.2073x over previous
//
#include <hip/hip_runtime.h>
#include <hip/hip_bf16.h>

#define NS 512
#define NV 32000
#define NB 16
#define NT 128

#ifndef __has_builtin
#define __has_builtin(x) 0
#endif

typedef int v8i __attribute__((ext_vector_type(8)));
typedef float v4f __attribute__((ext_vector_type(4)));

// ---------------------------------------------------------------------------
// e4m3fn (OCP) encode, x >= 0.
// ---------------------------------------------------------------------------
__device__ inline unsigned enc_e4m3(float x) {
    x = fminf(x, 448.0f);
    unsigned u = __float_as_uint(x);
    if (x < 0.015625f) {
        return (unsigned)(int)rintf(x * 512.0f);
    }
    unsigned u2 = u + 0x7FFFFu + ((u >> 20) & 1u);
    return (((u2 >> 23) - 120u) << 3) | ((u2 >> 20) & 7u);
}

__device__ inline unsigned pack4_e4m3(float a, float b, float c, float d) {
#if __has_builtin(__builtin_amdgcn_cvt_pk_fp8_f32)
    int v = __builtin_amdgcn_cvt_pk_fp8_f32(a, b, 0, false);
    v = __builtin_amdgcn_cvt_pk_fp8_f32(c, d, v, true);
    return (unsigned)v;
#else
    return enc_e4m3(a) | (enc_e4m3(b) << 8) | (enc_e4m3(c) << 16) | (enc_e4m3(d) << 24);
#endif
}

// DPP all-lane butterfly reduce within each row of 16 lanes.
#define DPPMAX(x, ctrl) \
    x = fmaxf(x, __int_as_float(__builtin_amdgcn_mov_dpp(__float_as_int(x), ctrl, 0xF, 0xF, true)))
#define DPPADD(x, ctrl) \
    x = x + __int_as_float(__builtin_amdgcn_mov_dpp(__float_as_int(x), ctrl, 0xF, 0xF, true))

// ---------------------------------------------------------------------------
// K1a: per-state logZ over vocab + emission gather, COALESCED store to
// em_lin_T[s][j] = exp(em[s][ids_j]) / Z_s * 2^-18.
// ---------------------------------------------------------------------------
__global__ __launch_bounds__(256) void k_emtok_T(
    const float* __restrict__ em, const int* __restrict__ ids,
    float* __restrict__ em_lin_T)
{
    const int s   = blockIdx.x;
    const int tid = threadIdx.x;
    const float* row = em + (size_t)s * NV;

    int idv[8];
#pragma unroll
    for (int k = 0; k < 8; ++k) idv[k] = ids[tid + 256 * k];
    float g[8];
#pragma unroll
    for (int k = 0; k < 8; ++k) g[k] = row[idv[k]];

    float sum = 0.f;
    const float4* row4 = (const float4*)row;
#pragma unroll 4
    for (int i = 0; i < 31; ++i) {
        float4 v = row4[tid + 256 * i];
        sum += __expf(v.x) + __expf(v.y) + __expf(v.z) + __expf(v.w);
    }
    sum += __expf(row[31744 + tid]);

#pragma unroll
    for (int off = 32; off; off >>= 1) sum += __shfl_down(sum, off);
    __shared__ float red[4];
    __shared__ float s_scale;
    if ((tid & 63) == 0) red[tid >> 6] = sum;
    __syncthreads();
    if (tid == 0) s_scale = (1.0f / ((red[0] + red[1]) + (red[2] + red[3]))) * 0x1p-18f;
    __syncthreads();
    const float scale = s_scale;

#pragma unroll
    for (int k = 0; k < 8; ++k)
        em_lin_T[(size_t)s * (NB * NT) + tid + 256 * k] = __expf(g[k]) * scale;
}

// ---------------------------------------------------------------------------
// K1b: transpose em_lin_T [512][2048] -> em_lin [2048][512]
// ---------------------------------------------------------------------------
__global__ __launch_bounds__(256) void k_tr(
    const float* __restrict__ emT, float* __restrict__ em_lin)
{
    __shared__ float tile[32][33];
    const int jb = blockIdx.x * 32;
    const int sb = blockIdx.y * 32;
    const int cc = threadIdx.x & 31;
    const int rr = threadIdx.x >> 5;
#pragma unroll
    for (int i = 0; i < 4; ++i) {
        int r = rr + 8 * i;
        tile[r][cc] = emT[(size_t)(sb + r) * (NB * NT) + jb + cc];
    }
    __syncthreads();
#pragma unroll
    for (int i = 0; i < 4; ++i) {
        int r = rr + 8 * i;
        em_lin[(size_t)(jb + r) * NS + sb + cc] = tile[cc][r];
    }
}

// ---------------------------------------------------------------------------
// K2a: zscale[k] = 1024 / sum_d exp(tm[k][d])
// ---------------------------------------------------------------------------
__global__ __launch_bounds__(64) void k_z(
    const float* __restrict__ tm, float* __restrict__ zscale)
{
    const int k    = blockIdx.x;
    const int lane = threadIdx.x;
    const float* row = tm + (size_t)k * NS;

    float4 a = ((const float4*)row)[lane * 2];
    float4 b = ((const float4*)row)[lane * 2 + 1];
    float sum = ((__expf(a.x) + __expf(a.y)) + (__expf(a.z) + __expf(a.w)))
              + ((__expf(b.x) + __expf(b.y)) + (__expf(b.z) + __expf(b.w)));
#pragma unroll
    for (int off = 32; off; off >>= 1) sum += __shfl_down(sum, off);
    if (lane == 0) zscale[k] = 1024.0f / sum;
}

// ---------------------------------------------------------------------------
// K2b: PT[d][k] = exp(tm[k][d]) * zscale[k], e4m3 fp8, LDS-transposed tiles.
// ---------------------------------------------------------------------------
__global__ __launch_bounds__(256) void k_pt2(
    const float* __restrict__ tm, const float* __restrict__ zscale,
    unsigned char* __restrict__ PT)
{
    __shared__ float tile[64][65];
    __shared__ float zs[64];
    const int kb  = blockIdx.x * 64;
    const int db  = blockIdx.y * 64;
    const int tid = threadIdx.x;
    const int c   = tid & 63;
    const int r0  = tid >> 6;

    if (tid < 64) zs[tid] = zscale[kb + tid];
#pragma unroll
    for (int i = 0; i < 16; ++i) {
        int r = r0 + 4 * i;
        tile[r][c] = tm[(size_t)(kb + r) * NS + db + c];
    }
    __syncthreads();

    const int d  = tid >> 2;
    const int ks = (tid & 3) * 16;
    unsigned px[4];
#pragma unroll
    for (int gq = 0; gq < 4; ++gq) {
        int k0 = ks + gq * 4;
        px[gq] = pack4_e4m3(__expf(tile[k0 + 0][d]) * zs[k0 + 0],
                            __expf(tile[k0 + 1][d]) * zs[k0 + 1],
                            __expf(tile[k0 + 2][d]) * zs[k0 + 2],
                            __expf(tile[k0 + 3][d]) * zs[k0 + 3]);
    }
    uint4 o; o.x = px[0]; o.y = px[1]; o.z = px[2]; o.w = px[3];
    *(uint4*)(PT + (size_t)(db + d) * NS + kb + ks) = o;
}

// ---------------------------------------------------------------------------
// K3 v4: 4 blocks x 4 batches (zero cross-block communication).
//   Batch of thread = lq (C-row 4*lq); A-rows {0,4,8,12} real, rest zero.
//   GLOBAL per-batch scale (exact shift bookkeeping, r4 numerics, absmax 0):
//   wave-max (DPP butterfly, row=16 = one batch) -> exponent byte to LDS ->
//   4-thread byte-max -> broadcast. fp8 MFMA, scales const 1.0.
//   A-read addresses hoisted (t-invariant); single Ew buffer (3 barriers).
// ---------------------------------------------------------------------------
__global__ __launch_bounds__(512, 2) void k_scan(
    const float* __restrict__ em_lin, const unsigned char* __restrict__ PT,
    const float* __restrict__ p, float* __restrict__ out)
{
    const int bb  = blockIdx.x;        // batch group: global batches bb*4+0..3
    const int tid = threadIdx.x;
    const int w   = tid >> 6;          // wave 0..7
    const int l   = tid & 63;          // lane
    const int lc  = l & 15;            // state-col within 16-tile
    const int lq  = l >> 4;            // local batch 0..3

    __shared__ unsigned Ew[16 * 128];  // 8 KB, [m][chunk^m swizzled]
    __shared__ unsigned wmE[8][4];     // per-wave max exponent byte per batch
    __shared__ unsigned mbuf[4];       // global exponent byte per batch
    __shared__ float    wm2[8][4];
    __shared__ float    sbuf[4];

    // ---- load B fragments (P, once) ----
    v8i B[4][4];
#pragma unroll
    for (int nt = 0; nt < 4; ++nt) {
#pragma unroll
        for (int kt = 0; kt < 4; ++kt) {
            const uint4* src = (const uint4*)(PT + (size_t)((w * 4 + nt) * 16 + lc) * NS + kt * 128 + lq * 32);
            uint4 lo = src[0], hi = src[1];
            v8i bb8;
            bb8[0] = (int)lo.x; bb8[1] = (int)lo.y; bb8[2] = (int)lo.z; bb8[3] = (int)lo.w;
            bb8[4] = (int)hi.x; bb8[5] = (int)hi.y; bb8[6] = (int)hi.z; bb8[7] = (int)hi.w;
            B[nt][kt] = bb8;
        }
    }

    // ---- prior softmax denominator ----
    float zp = 0.f;
#pragma unroll
    for (int i = 0; i < 8; ++i) zp += __expf(p[l * 8 + i]);
    DPPADD(zp, 0x128); DPPADD(zp, 0x124); DPPADD(zp, 0xB1); DPPADD(zp, 0x4E);
    float Zp = __int_as_float(__builtin_amdgcn_readlane(__float_as_int(zp), 0))
             + __int_as_float(__builtin_amdgcn_readlane(__float_as_int(zp), 16))
             + __int_as_float(__builtin_amdgcn_readlane(__float_as_int(zp), 32))
             + __int_as_float(__builtin_amdgcn_readlane(__float_as_int(zp), 48));
    const float invZp = 1.0f / Zp;

    const int dbase0 = w * 64 + lc;          // state d for nt: dbase0 + 16*nt
    const int gb     = bb * 4 + lq;          // global batch of this thread

    // ---- alpha_0 (linear; 2^-18 embedded in em_lin -> shift starts at 18) ----
    const float* epb0 = em_lin + (size_t)gb * (NT * NS) + dbase0;
    float alpha[4];
#pragma unroll
    for (int nt = 0; nt < 4; ++nt)
        alpha[nt] = __expf(p[dbase0 + 16 * nt]) * invZp * epb0[16 * nt];

    int gsum = 18;
    const unsigned sel1 = (l & 1) ? 0x07030501u : 0x02060004u;
    const unsigned sel2 = (l & 2) ? 0x07060302u : 0x01000504u;
    const int mrow = 4 * lq + (l & 3);

    // hoisted, t-invariant A-read uint4-indices and Ew write dword-indices
    int aidx[8];
#pragma unroll
    for (int kt = 0; kt < 4; ++kt) {
#pragma unroll
        for (int c = 0; c < 2; ++c)
            aidx[kt * 2 + c] = lc * 32 + (((kt * 8 + lq * 2 + c) ^ lc) & 31);
    }
    int widx[4];
#pragma unroll
    for (int nt = 0; nt < 4; ++nt)
        widx[nt] = mrow * 128 + ((((w * 4 + nt) ^ mrow) & 31) << 2) + (lc >> 2);

    const float* epb = epb0 + NS;            // emission pointer, stepped by NS

    for (int t = 1; t < NT; ++t) {
        // ---- prefetch em (consumed at end of iteration) ----
        float epf[4];
#pragma unroll
        for (int nt = 0; nt < 4; ++nt) epf[nt] = epb[16 * nt];
        epb += NS;

        // ---- per-batch wave max (row of 16 = one batch) ----
        float mx = fmaxf(fmaxf(alpha[0], alpha[1]), fmaxf(alpha[2], alpha[3]));
        DPPMAX(mx, 0x128); DPPMAX(mx, 0x124); DPPMAX(mx, 0xB1); DPPMAX(mx, 0x4E);
        if (lc == 0) wmE[w][lq] = __float_as_uint(mx) >> 23;
        __syncthreads();                                    // B1

        // ---- 4-thread cross-wave byte max ----
        if (tid < 4) {
            unsigned e0 = wmE[0][tid], e1 = wmE[1][tid], e2 = wmE[2][tid], e3 = wmE[3][tid];
            unsigned e4 = wmE[4][tid], e5 = wmE[5][tid], e6 = wmE[6][tid], e7 = wmE[7][tid];
            unsigned m01 = e0 > e1 ? e0 : e1,  m23 = e2 > e3 ? e2 : e3;
            unsigned m45 = e4 > e5 ? e4 : e5,  m67 = e6 > e7 ? e6 : e7;
            unsigned ma = m01 > m23 ? m01 : m23, mb = m45 > m67 ? m45 : m67;
            mbuf[tid] = ma > mb ? ma : mb;
        }
        __syncthreads();                                    // B2

        const unsigned eb = mbuf[lq];
        const float sc = __uint_as_float((261u - eb) << 23);   // 2^(134-eb)
        gsum += (int)eb - 126;

        // ---- e -> fp8 (global scale), DPP 4x4 byte transpose, Ew write ----
#pragma unroll
        for (int nt = 0; nt < 4; ++nt) {
            unsigned dw = pack4_e4m3(alpha[nt] * sc, 0.f, 0.f, 0.f);
            int tmp = __builtin_amdgcn_mov_dpp((int)dw, 0xB1, 0xF, 0xF, true);
            dw = __builtin_amdgcn_perm(dw, (unsigned)tmp, sel1);
            tmp = __builtin_amdgcn_mov_dpp((int)dw, 0x4E, 0xF, 0xF, true);
            dw = __builtin_amdgcn_perm(dw, (unsigned)tmp, sel2);
            Ew[widx[nt]] = dw;
        }
        __syncthreads();                                    // B3

        // ---- A fragments from LDS (hoisted swizzled indices) ----
        v8i A[4];
        const uint4* eb4 = (const uint4*)&Ew[0];
#pragma unroll
        for (int kt = 0; kt < 4; ++kt) {
            uint4 lo = eb4[aidx[kt * 2 + 0]];
            uint4 hi = eb4[aidx[kt * 2 + 1]];
            v8i aa;
            aa[0] = (int)lo.x; aa[1] = (int)lo.y; aa[2] = (int)lo.z; aa[3] = (int)lo.w;
            aa[4] = (int)hi.x; aa[5] = (int)hi.y; aa[6] = (int)hi.z; aa[7] = (int)hi.w;
            A[kt] = aa;
        }

        // ---- MFMA: Y = E . P (scales = 1.0) ----
        v4f C[4];
#pragma unroll
        for (int nt = 0; nt < 4; ++nt) { C[nt][0] = 0.f; C[nt][1] = 0.f; C[nt][2] = 0.f; C[nt][3] = 0.f; }
#pragma unroll
        for (int kt = 0; kt < 4; ++kt)
#pragma unroll
            for (int nt = 0; nt < 4; ++nt)
                C[nt] = __builtin_amdgcn_mfma_scale_f32_16x16x128_f8f6f4(
                            A[kt], B[nt][kt], C[nt], 0, 0, 0, 0x7F7F7F7F, 0, 0x7F7F7F7F);

        // ---- alpha update (linear); batch lq = C-row 4*lq = reg 0 ----
#pragma unroll
        for (int nt = 0; nt < 4; ++nt)
            alpha[nt] = C[nt][0] * epf[nt];
    }

    // ---- final: per-batch logsumexp over states ----
    {
        float sm = (alpha[0] + alpha[1]) + (alpha[2] + alpha[3]);
        DPPADD(sm, 0x128); DPPADD(sm, 0x124); DPPADD(sm, 0xB1); DPPADD(sm, 0x4E);
        if (lc == 0) wm2[w][lq] = sm;
        if (w == 0 && lc == 0) sbuf[lq] = (float)gsum;
    }
    __syncthreads();
    if (tid < 4) {
        float s8 = ((wm2[0][tid] + wm2[1][tid]) + (wm2[2][tid] + wm2[3][tid]))
                 + ((wm2[4][tid] + wm2[5][tid]) + (wm2[6][tid] + wm2[7][tid]));
        float L2 = __log2f(s8) + sbuf[tid];
        atomicAdd(out, -(0.693147180559945f / 16.0f) * L2);
    }
}

// ---------------------------------------------------------------------------
extern "C" void kernel_launch(void* const* d_in, const int* in_sizes, int n_in,
                              void* d_out, int out_size, void* d_ws, size_t ws_size,
                              hipStream_t stream)
{
    const int*   ids = (const int*)d_in[0];   // [16][128]
    const float* em  = (const float*)d_in[1]; // [512][32000]
    const float* tm  = (const float*)d_in[2]; // [512][512]
    const float* p   = (const float*)d_in[3]; // [512]
    float* out = (float*)d_out;

    float*          em_lin = (float*)d_ws;
    unsigned char*  PT     = (unsigned char*)d_ws + ((size_t)4 << 20);
    float*          zscale = (float*)((unsigned char*)d_ws + ((size_t)4 << 20) + ((size_t)256 << 10));
    float*          emT    = (float*)((unsigned char*)d_ws + ((size_t)4 << 20) + ((size_t)512 << 10));

    hipMemsetAsync(d_out, 0, sizeof(float), stream);

    k_emtok_T<<<NS, 256, 0, stream>>>(em, ids, emT);
    k_tr<<<dim3(64, 16), 256, 0, stream>>>(emT, em_lin);
    k_z<<<NS, 64, 0, stream>>>(tm, zscale);
    k_pt2<<<dim3(8, 8), 256, 0, stream>>>(tm, zscale, PT);
    k_scan<<<4, 512, 0, stream>>>(em_lin, PT, p, out);
}